// Round 2
// baseline (1212.640 us; speedup 1.0000x reference)
//
#include <hip/hip_runtime.h>

#define EMBED 64
#define RB 128  // rows per bucket (pass-1/pass-2 binned permutation)
#define SCAN_THREADS 256
#define SCAN_ITEMS 16
#define SCAN_TILE (SCAN_THREADS * SCAN_ITEMS)  // 4096

__global__ void zero_ints(int* __restrict__ p, int n) {
    int i = blockIdx.x * blockDim.x + threadIdx.x;
    if (i < n) p[i] = 0;
}

__global__ void hist_rows(const int* __restrict__ row, int* __restrict__ deg, int nnz) {
    int stride = gridDim.x * blockDim.x;
    for (int i = blockIdx.x * blockDim.x + threadIdx.x; i < nnz; i += stride)
        atomicAdd(&deg[row[i]], 1);
}

// Per-tile exclusive scan: writes tile-local exclusive prefix + tile sums.
__global__ void scan_tiles(const int* __restrict__ deg, int* __restrict__ offs,
                           int* __restrict__ tile_sums, int n) {
    __shared__ int sh[SCAN_THREADS];
    int t = threadIdx.x;
    int base = blockIdx.x * SCAN_TILE + t * SCAN_ITEMS;
    int vals[SCAN_ITEMS];
    int sum = 0;
#pragma unroll
    for (int k = 0; k < SCAN_ITEMS; ++k) {
        int idx = base + k;
        vals[k] = (idx < n) ? deg[idx] : 0;
        sum += vals[k];
    }
    sh[t] = sum;
    __syncthreads();
    for (int off = 1; off < SCAN_THREADS; off <<= 1) {
        int v = (t >= off) ? sh[t - off] : 0;
        __syncthreads();
        sh[t] += v;
        __syncthreads();
    }
    int excl = sh[t] - sum;
    if (t == SCAN_THREADS - 1) tile_sums[blockIdx.x] = sh[t];
    int run = excl;
#pragma unroll
    for (int k = 0; k < SCAN_ITEMS; ++k) {
        int idx = base + k;
        if (idx < n) offs[idx] = run;
        run += vals[k];
    }
}

__global__ void scan_bases(const int* __restrict__ tile_sums, int* __restrict__ tile_base,
                           int ntiles) {
    if (threadIdx.x == 0 && blockIdx.x == 0) {
        int run = 0;
        for (int i = 0; i < ntiles; ++i) { tile_base[i] = run; run += tile_sums[i]; }
        tile_base[ntiles] = run;
    }
}

__global__ void add_bases(int* __restrict__ offs, const int* __restrict__ tile_base,
                          int n, int ntiles) {
    int i = blockIdx.x * blockDim.x + threadIdx.x;
    if (i < n) offs[i] += tile_base[i / SCAN_TILE];
    if (i == 0) offs[n] = tile_base[ntiles];
}

__global__ void init_bcur(const int* __restrict__ offs, int* __restrict__ bcur,
                          int nb, int n_nodes) {
    int b = blockIdx.x * blockDim.x + threadIdx.x;
    if (b < nb) bcur[b] = offs[min(b * RB, n_nodes)];
}

// Pass 1: bin edges by row-bucket. ~1172 dense write fronts -> cachelines fill
// before eviction (vs 150K-wide random scatter).
__global__ void pass1_bin(const int* __restrict__ row, const int* __restrict__ col,
                          const float* __restrict__ vals, int* __restrict__ bcur,
                          int2* __restrict__ tmp, int* __restrict__ trow, int nnz) {
    int stride = gridDim.x * blockDim.x;
    for (int i = blockIdx.x * blockDim.x + threadIdx.x; i < nnz; i += stride) {
        int r = row[i];
        int slot = atomicAdd(&bcur[r / RB], 1);
        tmp[slot] = make_int2(col[i], __float_as_int(vals[i]));
        trow[slot] = r;
    }
}

// Pass 2: one block per bucket; LDS cursors; writes confined to the bucket's
// contiguous CSR range (L2-resident).
__global__ __launch_bounds__(256) void pass2_place(const int* __restrict__ offs,
                                                   const int* __restrict__ trow,
                                                   const int2* __restrict__ tmp,
                                                   int2* __restrict__ edat, int n_nodes) {
    __shared__ int lcur[RB];
    int b = blockIdx.x;
    int r0 = b * RB;
    int r1 = min(r0 + RB, n_nodes);
    int t = threadIdx.x;
    if (r0 >= n_nodes) return;
    if (t < r1 - r0) lcur[t] = offs[r0 + t];
    __syncthreads();
    int bstart = offs[r0];
    int bend = offs[r1];
    for (int e = bstart + t; e < bend; e += 256) {
        int r = trow[e];
        int2 v = tmp[e];
        int slot = atomicAdd(&lcur[r - r0], 1);
        edat[slot] = v;
    }
}

__global__ void concat_copy(const float* __restrict__ ue, const float* __restrict__ ie,
                            float* __restrict__ x, int nu4, int tot4) {
    int stride = gridDim.x * blockDim.x;
    for (int i = blockIdx.x * blockDim.x + threadIdx.x; i < tot4; i += stride) {
        float4 v = (i < nu4) ? ((const float4*)ue)[i] : ((const float4*)ie)[i - nu4];
        ((float4*)x)[i] = v;
    }
}

// One wave per node; 4 edge-groups x 16 lanes x float4; shuffle-reduce across groups.
__global__ __launch_bounds__(256) void spmm(const int* __restrict__ offs,
                                            const int2* __restrict__ edat,
                                            const float* __restrict__ x,
                                            float* __restrict__ y, int n_nodes) {
    int wave = blockIdx.x * (blockDim.x >> 6) + (threadIdx.x >> 6);
    if (wave >= n_nodes) return;
    int lane = threadIdx.x & 63;
    int g = lane >> 4;    // edge subgroup 0..3
    int l16 = lane & 15;  // dim-quad
    int start = offs[wave];
    int end = offs[wave + 1];
    float4 acc = make_float4(0.f, 0.f, 0.f, 0.f);
    for (int e = start + g; e < end; e += 4) {
        int2 ev = edat[e];
        float v = __int_as_float(ev.y);
        float4 xv = *(const float4*)(x + (size_t)ev.x * EMBED + l16 * 4);
        acc.x += v * xv.x;
        acc.y += v * xv.y;
        acc.z += v * xv.z;
        acc.w += v * xv.w;
    }
#pragma unroll
    for (int m = 16; m <= 32; m <<= 1) {
        acc.x += __shfl_xor(acc.x, m);
        acc.y += __shfl_xor(acc.y, m);
        acc.z += __shfl_xor(acc.z, m);
        acc.w += __shfl_xor(acc.w, m);
    }
    if (g == 0)
        *(float4*)(y + (size_t)wave * EMBED + l16 * 4) = acc;
}

__global__ void gather_out(const float* __restrict__ x, const int* __restrict__ users,
                           const int* __restrict__ pos, const int* __restrict__ neg,
                           float* __restrict__ out, int batch, int n_users, int first) {
    int idx = blockIdx.x * blockDim.x + threadIdx.x;
    int total = 3 * batch * EMBED;
    if (idx >= total) return;
    int r = idx >> 6;
    int d = idx & 63;
    int which = r / batch;
    int b = r - which * batch;
    int node = (which == 0) ? users[b] : ((which == 1) ? (n_users + pos[b]) : (n_users + neg[b]));
    float v = 0.25f * x[(size_t)node * EMBED + d];
    if (first) out[idx] = v;
    else out[idx] += v;
}

extern "C" void kernel_launch(void* const* d_in, const int* in_sizes, int n_in,
                              void* d_out, int out_size, void* d_ws, size_t ws_size,
                              hipStream_t stream) {
    const float* user_emb = (const float*)d_in[0];
    const float* item_emb = (const float*)d_in[1];
    const int* row = (const int*)d_in[2];
    const int* col = (const int*)d_in[3];
    const float* vals = (const float*)d_in[4];
    const int* users = (const int*)d_in[5];
    const int* pos = (const int*)d_in[6];
    const int* neg = (const int*)d_in[7];
    float* out = (float*)d_out;

    int n_users = in_sizes[0] / EMBED;
    int n_items = in_sizes[1] / EMBED;
    int n_nodes = n_users + n_items;
    int nnz = in_sizes[2];
    int batch = in_sizes[5];
    int nb = (n_nodes + RB - 1) / RB;

    char* p = (char*)d_ws;
    auto alloc = [&](size_t bytes) -> void* {
        void* r = (void*)p;
        p += (bytes + 255) & ~(size_t)255;
        return r;
    };
    int ntiles = (n_nodes + SCAN_TILE - 1) / SCAN_TILE;
    int* deg = (int*)alloc(sizeof(int) * (size_t)n_nodes);
    int* offs = (int*)alloc(sizeof(int) * (size_t)(n_nodes + 1));
    int* bcur = (int*)alloc(sizeof(int) * (size_t)nb);
    int* tile_sums = (int*)alloc(sizeof(int) * (size_t)ntiles);
    int* tile_base = (int*)alloc(sizeof(int) * (size_t)(ntiles + 1));
    int2* edat = (int2*)alloc(sizeof(int2) * (size_t)nnz);
    float* bufA = (float*)alloc(sizeof(float) * (size_t)n_nodes * EMBED);
    float* bufB = (float*)alloc(sizeof(float) * (size_t)n_nodes * EMBED);
    if ((size_t)(p - (char*)d_ws) > ws_size) return;  // workspace too small: bail visibly
    // tmp/trow are consumed before concat/spmm touch bufA/bufB -> alias them.
    int2* tmp = (int2*)bufA;   // nnz*8B <= n_nodes*256B
    int* trow = (int*)bufB;    // nnz*4B <= n_nodes*256B

    zero_ints<<<(n_nodes + 255) / 256, 256, 0, stream>>>(deg, n_nodes);
    hist_rows<<<2048, 256, 0, stream>>>(row, deg, nnz);
    scan_tiles<<<ntiles, SCAN_THREADS, 0, stream>>>(deg, offs, tile_sums, n_nodes);
    scan_bases<<<1, 64, 0, stream>>>(tile_sums, tile_base, ntiles);
    add_bases<<<(n_nodes + 255) / 256, 256, 0, stream>>>(offs, tile_base, n_nodes, ntiles);
    init_bcur<<<(nb + 255) / 256, 256, 0, stream>>>(offs, bcur, nb, n_nodes);
    pass1_bin<<<2048, 256, 0, stream>>>(row, col, vals, bcur, tmp, trow, nnz);
    pass2_place<<<nb, 256, 0, stream>>>(offs, trow, tmp, edat, n_nodes);

    int tot4 = n_nodes * EMBED / 4;
    int nu4 = n_users * EMBED / 4;
    concat_copy<<<2048, 256, 0, stream>>>(user_emb, item_emb, bufA, nu4, tot4);

    int gblocks = (3 * batch * EMBED + 255) / 256;
    int spmm_blocks = (n_nodes + 3) / 4;

    gather_out<<<gblocks, 256, 0, stream>>>(bufA, users, pos, neg, out, batch, n_users, 1);
    spmm<<<spmm_blocks, 256, 0, stream>>>(offs, edat, bufA, bufB, n_nodes);
    gather_out<<<gblocks, 256, 0, stream>>>(bufB, users, pos, neg, out, batch, n_users, 0);
    spmm<<<spmm_blocks, 256, 0, stream>>>(offs, edat, bufB, bufA, n_nodes);
    gather_out<<<gblocks, 256, 0, stream>>>(bufA, users, pos, neg, out, batch, n_users, 0);
    spmm<<<spmm_blocks, 256, 0, stream>>>(offs, edat, bufA, bufB, n_nodes);
    gather_out<<<gblocks, 256, 0, stream>>>(bufB, users, pos, neg, out, batch, n_users, 0);
}

// Round 3
// 616.470 us; speedup vs baseline: 1.9671x; 1.9671x over previous
//
#include <hip/hip_runtime.h>

#define EMBED 64
#define BSHIFT 9
#define BROWS 512      // rows per coarse bucket
#define NGROUPS 256    // passA/passB blocks (private write fronts)
#define MAXNB 512      // max buckets supported by LDS arrays (nb=293 here)
#define SCAN_THREADS 256
#define SCAN_ITEMS 16
#define SCAN_TILE (SCAN_THREADS * SCAN_ITEMS)  // 4096

__global__ void zero_ints(int* __restrict__ p, int n) {
    int i = blockIdx.x * blockDim.x + threadIdx.x;
    if (i < n) p[i] = 0;
}

__global__ void hist_rows(const int* __restrict__ row, int* __restrict__ deg, int nnz) {
    int stride = gridDim.x * blockDim.x;
    for (int i = blockIdx.x * blockDim.x + threadIdx.x; i < nnz; i += stride)
        atomicAdd(&deg[row[i]], 1);
}

// Generic per-tile exclusive scan: in -> out (tile-local) + tile sums.
__global__ void scan_tiles(const int* __restrict__ in, int* __restrict__ out,
                           int* __restrict__ tile_sums, int n) {
    __shared__ int sh[SCAN_THREADS];
    int t = threadIdx.x;
    int base = blockIdx.x * SCAN_TILE + t * SCAN_ITEMS;
    int vals[SCAN_ITEMS];
    int sum = 0;
#pragma unroll
    for (int k = 0; k < SCAN_ITEMS; ++k) {
        int idx = base + k;
        vals[k] = (idx < n) ? in[idx] : 0;
        sum += vals[k];
    }
    sh[t] = sum;
    __syncthreads();
    for (int off = 1; off < SCAN_THREADS; off <<= 1) {
        int v = (t >= off) ? sh[t - off] : 0;
        __syncthreads();
        sh[t] += v;
        __syncthreads();
    }
    int excl = sh[t] - sum;
    if (t == SCAN_THREADS - 1) tile_sums[blockIdx.x] = sh[t];
    int run = excl;
#pragma unroll
    for (int k = 0; k < SCAN_ITEMS; ++k) {
        int idx = base + k;
        if (idx < n) out[idx] = run;
        run += vals[k];
    }
}

__global__ void scan_bases(const int* __restrict__ tile_sums, int* __restrict__ tile_base,
                           int ntiles) {
    if (threadIdx.x == 0 && blockIdx.x == 0) {
        int run = 0;
        for (int i = 0; i < ntiles; ++i) { tile_base[i] = run; run += tile_sums[i]; }
        tile_base[ntiles] = run;
    }
}

__global__ void add_bases(int* __restrict__ arr, const int* __restrict__ tile_base,
                          int n, int ntiles) {
    int i = blockIdx.x * blockDim.x + threadIdx.x;
    if (i < n) arr[i] += tile_base[i / SCAN_TILE];
    if (i == 0) arr[n] = tile_base[ntiles];
}

// passA: per-block LDS histogram over coarse buckets -> cnt[bucket][block].
__global__ __launch_bounds__(256) void passA_hist(const int* __restrict__ row,
                                                  int* __restrict__ cnt,
                                                  int nnz, int nb, int epb) {
    __shared__ int hist[MAXNB];
    int g = blockIdx.x, t = threadIdx.x;
    for (int b = t; b < nb; b += 256) hist[b] = 0;
    __syncthreads();
    int i0 = g * epb, i1 = min(i0 + epb, nnz);
    for (int i = i0 + t; i < i1; i += 256) atomicAdd(&hist[row[i] >> BSHIFT], 1);
    __syncthreads();
    for (int b = t; b < nb; b += 256) cnt[b * NGROUPS + g] = hist[b];
}

// passB: deterministic scatter into block-private dense fronts (LDS cursors,
// no global atomics, full-cacheline writes).
__global__ __launch_bounds__(256) void passB_scatter(const int* __restrict__ row,
                                                     const int* __restrict__ col,
                                                     const float* __restrict__ vals,
                                                     const int* __restrict__ cbase,
                                                     int4* __restrict__ tmp4,
                                                     int nnz, int nb, int epb) {
    __shared__ int lcur[MAXNB];
    int g = blockIdx.x, t = threadIdx.x;
    for (int b = t; b < nb; b += 256) lcur[b] = cbase[b * NGROUPS + g];
    __syncthreads();
    int i0 = g * epb, i1 = min(i0 + epb, nnz);
    for (int i = i0 + t; i < i1; i += 256) {
        int r = row[i];
        int slot = atomicAdd(&lcur[r >> BSHIFT], 1);
        tmp4[slot] = make_int4(col[i], __float_as_int(vals[i]), r, 0);
    }
}

// pass2: one block per bucket; LDS row-cursors; writes confined to the
// bucket's contiguous CSR span (~90 KB, L2-resident).
__global__ __launch_bounds__(256) void pass2_place(const int* __restrict__ offs,
                                                   const int4* __restrict__ tmp4,
                                                   int2* __restrict__ edat, int n_nodes) {
    __shared__ int lcur[BROWS];
    int b = blockIdx.x;
    int t = threadIdx.x;
    int r0 = b * BROWS;
    int r1 = min(r0 + BROWS, n_nodes);
    if (r0 >= n_nodes) return;
    for (int r = t; r < r1 - r0; r += 256) lcur[r] = offs[r0 + r];
    __syncthreads();
    int es = offs[r0];
    int ee = offs[r1];
    for (int e = es + t; e < ee; e += 256) {
        int4 v = tmp4[e];
        int slot = atomicAdd(&lcur[v.z - r0], 1);
        edat[slot] = make_int2(v.x, v.y);
    }
}

__global__ void concat_copy(const float* __restrict__ ue, const float* __restrict__ ie,
                            float* __restrict__ x, int nu4, int tot4) {
    int stride = gridDim.x * blockDim.x;
    for (int i = blockIdx.x * blockDim.x + threadIdx.x; i < tot4; i += stride) {
        float4 v = (i < nu4) ? ((const float4*)ue)[i] : ((const float4*)ie)[i - nu4];
        ((float4*)x)[i] = v;
    }
}

// One wave per node; 4 edge-groups x 16 lanes x float4; shuffle-reduce across groups.
__global__ __launch_bounds__(256) void spmm(const int* __restrict__ offs,
                                            const int2* __restrict__ edat,
                                            const float* __restrict__ x,
                                            float* __restrict__ y, int n_nodes) {
    int wave = blockIdx.x * (blockDim.x >> 6) + (threadIdx.x >> 6);
    if (wave >= n_nodes) return;
    int lane = threadIdx.x & 63;
    int g = lane >> 4;    // edge subgroup 0..3
    int l16 = lane & 15;  // dim-quad
    int start = offs[wave];
    int end = offs[wave + 1];
    float4 acc = make_float4(0.f, 0.f, 0.f, 0.f);
    for (int e = start + g; e < end; e += 4) {
        int2 ev = edat[e];
        float v = __int_as_float(ev.y);
        float4 xv = *(const float4*)(x + (size_t)ev.x * EMBED + l16 * 4);
        acc.x += v * xv.x;
        acc.y += v * xv.y;
        acc.z += v * xv.z;
        acc.w += v * xv.w;
    }
#pragma unroll
    for (int m = 16; m <= 32; m <<= 1) {
        acc.x += __shfl_xor(acc.x, m);
        acc.y += __shfl_xor(acc.y, m);
        acc.z += __shfl_xor(acc.z, m);
        acc.w += __shfl_xor(acc.w, m);
    }
    if (g == 0)
        *(float4*)(y + (size_t)wave * EMBED + l16 * 4) = acc;
}

__global__ void gather_out(const float* __restrict__ x, const int* __restrict__ users,
                           const int* __restrict__ pos, const int* __restrict__ neg,
                           float* __restrict__ out, int batch, int n_users, int first) {
    int idx = blockIdx.x * blockDim.x + threadIdx.x;
    int total = 3 * batch * EMBED;
    if (idx >= total) return;
    int r = idx >> 6;
    int d = idx & 63;
    int which = r / batch;
    int b = r - which * batch;
    int node = (which == 0) ? users[b] : ((which == 1) ? (n_users + pos[b]) : (n_users + neg[b]));
    float v = 0.25f * x[(size_t)node * EMBED + d];
    if (first) out[idx] = v;
    else out[idx] += v;
}

extern "C" void kernel_launch(void* const* d_in, const int* in_sizes, int n_in,
                              void* d_out, int out_size, void* d_ws, size_t ws_size,
                              hipStream_t stream) {
    const float* user_emb = (const float*)d_in[0];
    const float* item_emb = (const float*)d_in[1];
    const int* row = (const int*)d_in[2];
    const int* col = (const int*)d_in[3];
    const float* vals = (const float*)d_in[4];
    const int* users = (const int*)d_in[5];
    const int* pos = (const int*)d_in[6];
    const int* neg = (const int*)d_in[7];
    float* out = (float*)d_out;

    int n_users = in_sizes[0] / EMBED;
    int n_items = in_sizes[1] / EMBED;
    int n_nodes = n_users + n_items;
    int nnz = in_sizes[2];
    int batch = in_sizes[5];
    int nb = (n_nodes + BROWS - 1) / BROWS;   // 293
    int n2 = nb * NGROUPS;                    // 75008
    int epb = (nnz + NGROUPS - 1) / NGROUPS;  // 12500

    char* p = (char*)d_ws;
    auto alloc = [&](size_t bytes) -> void* {
        void* r = (void*)p;
        p += (bytes + 255) & ~(size_t)255;
        return r;
    };
    int ntiles1 = (n_nodes + SCAN_TILE - 1) / SCAN_TILE;
    int ntiles2 = (n2 + SCAN_TILE - 1) / SCAN_TILE;
    int ntiles_max = ntiles1 > ntiles2 ? ntiles1 : ntiles2;
    int* deg = (int*)alloc(sizeof(int) * (size_t)n_nodes);
    int* offs = (int*)alloc(sizeof(int) * (size_t)(n_nodes + 1));
    int* cnt = (int*)alloc(sizeof(int) * (size_t)n2);
    int* cbase = (int*)alloc(sizeof(int) * (size_t)(n2 + 1));
    int* tile_sums = (int*)alloc(sizeof(int) * (size_t)ntiles_max);
    int* tile_base = (int*)alloc(sizeof(int) * (size_t)(ntiles_max + 1));
    int2* edat = (int2*)alloc(sizeof(int2) * (size_t)nnz);
    float* bufA = (float*)alloc(sizeof(float) * (size_t)n_nodes * EMBED);
    float* bufB = (float*)alloc(sizeof(float) * (size_t)n_nodes * EMBED);
    if ((size_t)(p - (char*)d_ws) > ws_size) return;  // workspace too small: bail visibly
    // tmp4 (nnz*16B = 51.2MB) aliases bufA+bufB (76.8MB contiguous); consumed by
    // pass2 before concat/spmm write bufA/bufB.
    int4* tmp4 = (int4*)bufA;

    zero_ints<<<(n_nodes + 255) / 256, 256, 0, stream>>>(deg, n_nodes);
    hist_rows<<<2048, 256, 0, stream>>>(row, deg, nnz);
    scan_tiles<<<ntiles1, SCAN_THREADS, 0, stream>>>(deg, offs, tile_sums, n_nodes);
    scan_bases<<<1, 64, 0, stream>>>(tile_sums, tile_base, ntiles1);
    add_bases<<<(n_nodes + 255) / 256, 256, 0, stream>>>(offs, tile_base, n_nodes, ntiles1);

    passA_hist<<<NGROUPS, 256, 0, stream>>>(row, cnt, nnz, nb, epb);
    scan_tiles<<<ntiles2, SCAN_THREADS, 0, stream>>>(cnt, cbase, tile_sums, n2);
    scan_bases<<<1, 64, 0, stream>>>(tile_sums, tile_base, ntiles2);
    add_bases<<<(n2 + 255) / 256, 256, 0, stream>>>(cbase, tile_base, n2, ntiles2);
    passB_scatter<<<NGROUPS, 256, 0, stream>>>(row, col, vals, cbase, tmp4, nnz, nb, epb);
    pass2_place<<<nb, 256, 0, stream>>>(offs, tmp4, edat, n_nodes);

    int tot4 = n_nodes * EMBED / 4;
    int nu4 = n_users * EMBED / 4;
    concat_copy<<<2048, 256, 0, stream>>>(user_emb, item_emb, bufA, nu4, tot4);

    int gblocks = (3 * batch * EMBED + 255) / 256;
    int spmm_blocks = (n_nodes + 3) / 4;

    gather_out<<<gblocks, 256, 0, stream>>>(bufA, users, pos, neg, out, batch, n_users, 1);
    spmm<<<spmm_blocks, 256, 0, stream>>>(offs, edat, bufA, bufB, n_nodes);
    gather_out<<<gblocks, 256, 0, stream>>>(bufB, users, pos, neg, out, batch, n_users, 0);
    spmm<<<spmm_blocks, 256, 0, stream>>>(offs, edat, bufB, bufA, n_nodes);
    gather_out<<<gblocks, 256, 0, stream>>>(bufA, users, pos, neg, out, batch, n_users, 0);
    spmm<<<spmm_blocks, 256, 0, stream>>>(offs, edat, bufA, bufB, n_nodes);
    gather_out<<<gblocks, 256, 0, stream>>>(bufB, users, pos, neg, out, batch, n_users, 0);
}

// Round 4
// 499.129 us; speedup vs baseline: 2.4295x; 1.2351x over previous
//
#include <hip/hip_runtime.h>

#define EMBED 64
#define BSHIFT 9
#define BROWS 512      // rows per coarse bucket
#define NGROUPS 256    // passA/passB blocks (private write fronts)
#define MAXNB 512      // max buckets supported by LDS arrays (nb=293 here)
#define SCAN_THREADS 256
#define SCAN_ITEMS 16
#define SCAN_TILE (SCAN_THREADS * SCAN_ITEMS)  // 4096

// Generic per-tile exclusive scan: in -> out (tile-local) + tile sums.
__global__ void scan_tiles(const int* __restrict__ in, int* __restrict__ out,
                           int* __restrict__ tile_sums, int n) {
    __shared__ int sh[SCAN_THREADS];
    int t = threadIdx.x;
    int base = blockIdx.x * SCAN_TILE + t * SCAN_ITEMS;
    int vals[SCAN_ITEMS];
    int sum = 0;
#pragma unroll
    for (int k = 0; k < SCAN_ITEMS; ++k) {
        int idx = base + k;
        vals[k] = (idx < n) ? in[idx] : 0;
        sum += vals[k];
    }
    sh[t] = sum;
    __syncthreads();
    for (int off = 1; off < SCAN_THREADS; off <<= 1) {
        int v = (t >= off) ? sh[t - off] : 0;
        __syncthreads();
        sh[t] += v;
        __syncthreads();
    }
    int excl = sh[t] - sum;
    if (t == SCAN_THREADS - 1) tile_sums[blockIdx.x] = sh[t];
    int run = excl;
#pragma unroll
    for (int k = 0; k < SCAN_ITEMS; ++k) {
        int idx = base + k;
        if (idx < n) out[idx] = run;
        run += vals[k];
    }
}

__global__ void scan_bases(const int* __restrict__ tile_sums, int* __restrict__ tile_base,
                           int ntiles) {
    if (threadIdx.x == 0 && blockIdx.x == 0) {
        int run = 0;
        for (int i = 0; i < ntiles; ++i) { tile_base[i] = run; run += tile_sums[i]; }
        tile_base[ntiles] = run;
    }
}

__global__ void add_bases(int* __restrict__ arr, const int* __restrict__ tile_base,
                          int n, int ntiles) {
    int i = blockIdx.x * blockDim.x + threadIdx.x;
    if (i < n) arr[i] += tile_base[i / SCAN_TILE];
    if (i == 0) arr[n] = tile_base[ntiles];
}

// passA: per-block LDS histogram over coarse buckets -> cnt[bucket][block].
__global__ __launch_bounds__(256) void passA_hist(const int* __restrict__ row,
                                                  int* __restrict__ cnt,
                                                  int nnz, int nb, int epb) {
    __shared__ int hist[MAXNB];
    int g = blockIdx.x, t = threadIdx.x;
    for (int b = t; b < nb; b += 256) hist[b] = 0;
    __syncthreads();
    int i0 = g * epb, i1 = min(i0 + epb, nnz);
    for (int i = i0 + t; i < i1; i += 256) atomicAdd(&hist[row[i] >> BSHIFT], 1);
    __syncthreads();
    for (int b = t; b < nb; b += 256) cnt[b * NGROUPS + g] = hist[b];
}

// passB: deterministic scatter into block-private dense fronts (LDS cursors,
// no global atomics, full-cacheline writes). 12 B/edge split layout.
__global__ __launch_bounds__(256) void passB_scatter(const int* __restrict__ row,
                                                     const int* __restrict__ col,
                                                     const float* __restrict__ vals,
                                                     const int* __restrict__ cbase,
                                                     int2* __restrict__ tmp,
                                                     int* __restrict__ trow,
                                                     int nnz, int nb, int epb) {
    __shared__ int lcur[MAXNB];
    int g = blockIdx.x, t = threadIdx.x;
    for (int b = t; b < nb; b += 256) lcur[b] = cbase[b * NGROUPS + g];
    __syncthreads();
    int i0 = g * epb, i1 = min(i0 + epb, nnz);
    for (int i = i0 + t; i < i1; i += 256) {
        int r = row[i];
        int slot = atomicAdd(&lcur[r >> BSHIFT], 1);
        tmp[slot] = make_int2(col[i], __float_as_int(vals[i]));
        trow[slot] = r;
    }
}

// deg via LDS-only atomics: one block per bucket histograms its contiguous
// (bucket-grouped) edge range -> dense deg writes. No global atomics.
__global__ __launch_bounds__(256) void deg_from_bins(const int* __restrict__ cbase,
                                                     const int* __restrict__ trow,
                                                     int* __restrict__ deg,
                                                     int n_nodes, int nb) {
    __shared__ int hist[BROWS];
    int b = blockIdx.x, t = threadIdx.x;
    int r0 = b * BROWS;
    int r1 = min(r0 + BROWS, n_nodes);
    for (int r = t; r < BROWS; r += 256) hist[r] = 0;
    __syncthreads();
    int es = cbase[b * NGROUPS];
    int ee = cbase[(b + 1) * NGROUPS];  // cbase[n2] == nnz
    for (int e = es + t; e < ee; e += 256) atomicAdd(&hist[trow[e] - r0], 1);
    __syncthreads();
    for (int r = r0 + t; r < r1; r += 256) deg[r] = hist[r - r0];
}

// pass2: one block per bucket; LDS row-cursors; writes confined to the
// bucket's contiguous CSR span (~90 KB, L2-resident).
__global__ __launch_bounds__(256) void pass2_place(const int* __restrict__ offs,
                                                   const int* __restrict__ trow,
                                                   const int2* __restrict__ tmp,
                                                   int2* __restrict__ edat, int n_nodes) {
    __shared__ int lcur[BROWS];
    int b = blockIdx.x;
    int t = threadIdx.x;
    int r0 = b * BROWS;
    int r1 = min(r0 + BROWS, n_nodes);
    if (r0 >= n_nodes) return;
    for (int r = t; r < r1 - r0; r += 256) lcur[r] = offs[r0 + r];
    __syncthreads();
    int es = offs[r0];
    int ee = offs[r1];
    for (int e = es + t; e < ee; e += 256) {
        int r = trow[e];
        int2 v = tmp[e];
        int slot = atomicAdd(&lcur[r - r0], 1);
        edat[slot] = v;
    }
}

__global__ void concat_copy(const float* __restrict__ ue, const float* __restrict__ ie,
                            float* __restrict__ x, int nu4, int tot4) {
    int stride = gridDim.x * blockDim.x;
    for (int i = blockIdx.x * blockDim.x + threadIdx.x; i < tot4; i += stride) {
        float4 v = (i < nu4) ? ((const float4*)ue)[i] : ((const float4*)ie)[i - nu4];
        ((float4*)x)[i] = v;
    }
}

// One wave per node; 4 edge-groups x 16 lanes x float4; shuffle-reduce across groups.
__global__ __launch_bounds__(256) void spmm(const int* __restrict__ offs,
                                            const int2* __restrict__ edat,
                                            const float* __restrict__ x,
                                            float* __restrict__ y, int n_nodes) {
    int wave = blockIdx.x * (blockDim.x >> 6) + (threadIdx.x >> 6);
    if (wave >= n_nodes) return;
    int lane = threadIdx.x & 63;
    int g = lane >> 4;    // edge subgroup 0..3
    int l16 = lane & 15;  // dim-quad
    int start = offs[wave];
    int end = offs[wave + 1];
    float4 acc = make_float4(0.f, 0.f, 0.f, 0.f);
    for (int e = start + g; e < end; e += 4) {
        int2 ev = edat[e];
        float v = __int_as_float(ev.y);
        float4 xv = *(const float4*)(x + (size_t)ev.x * EMBED + l16 * 4);
        acc.x += v * xv.x;
        acc.y += v * xv.y;
        acc.z += v * xv.z;
        acc.w += v * xv.w;
    }
#pragma unroll
    for (int m = 16; m <= 32; m <<= 1) {
        acc.x += __shfl_xor(acc.x, m);
        acc.y += __shfl_xor(acc.y, m);
        acc.z += __shfl_xor(acc.z, m);
        acc.w += __shfl_xor(acc.w, m);
    }
    if (g == 0)
        *(float4*)(y + (size_t)wave * EMBED + l16 * 4) = acc;
}

__global__ void gather_out(const float* __restrict__ x, const int* __restrict__ users,
                           const int* __restrict__ pos, const int* __restrict__ neg,
                           float* __restrict__ out, int batch, int n_users, int first) {
    int idx = blockIdx.x * blockDim.x + threadIdx.x;
    int total = 3 * batch * EMBED;
    if (idx >= total) return;
    int r = idx >> 6;
    int d = idx & 63;
    int which = r / batch;
    int b = r - which * batch;
    int node = (which == 0) ? users[b] : ((which == 1) ? (n_users + pos[b]) : (n_users + neg[b]));
    float v = 0.25f * x[(size_t)node * EMBED + d];
    if (first) out[idx] = v;
    else out[idx] += v;
}

extern "C" void kernel_launch(void* const* d_in, const int* in_sizes, int n_in,
                              void* d_out, int out_size, void* d_ws, size_t ws_size,
                              hipStream_t stream) {
    const float* user_emb = (const float*)d_in[0];
    const float* item_emb = (const float*)d_in[1];
    const int* row = (const int*)d_in[2];
    const int* col = (const int*)d_in[3];
    const float* vals = (const float*)d_in[4];
    const int* users = (const int*)d_in[5];
    const int* pos = (const int*)d_in[6];
    const int* neg = (const int*)d_in[7];
    float* out = (float*)d_out;

    int n_users = in_sizes[0] / EMBED;
    int n_items = in_sizes[1] / EMBED;
    int n_nodes = n_users + n_items;
    int nnz = in_sizes[2];
    int batch = in_sizes[5];
    int nb = (n_nodes + BROWS - 1) / BROWS;   // 293
    int n2 = nb * NGROUPS;                    // 75008
    int epb = (nnz + NGROUPS - 1) / NGROUPS;  // 12500

    char* p = (char*)d_ws;
    auto alloc = [&](size_t bytes) -> void* {
        void* r = (void*)p;
        p += (bytes + 255) & ~(size_t)255;
        return r;
    };
    int ntiles1 = (n_nodes + SCAN_TILE - 1) / SCAN_TILE;
    int ntiles2 = (n2 + SCAN_TILE - 1) / SCAN_TILE;
    int ntiles_max = ntiles1 > ntiles2 ? ntiles1 : ntiles2;
    int* deg = (int*)alloc(sizeof(int) * (size_t)n_nodes);
    int* offs = (int*)alloc(sizeof(int) * (size_t)(n_nodes + 1));
    int* cnt = (int*)alloc(sizeof(int) * (size_t)n2);
    int* cbase = (int*)alloc(sizeof(int) * (size_t)(n2 + 1));
    int* tile_sums = (int*)alloc(sizeof(int) * (size_t)ntiles_max);
    int* tile_base = (int*)alloc(sizeof(int) * (size_t)(ntiles_max + 1));
    int2* edat = (int2*)alloc(sizeof(int2) * (size_t)nnz);
    float* bufA = (float*)alloc(sizeof(float) * (size_t)n_nodes * EMBED);
    float* bufB = (float*)alloc(sizeof(float) * (size_t)n_nodes * EMBED);
    if ((size_t)(p - (char*)d_ws) > ws_size) return;  // workspace too small: bail visibly
    // tmp (25.6MB) aliases bufA (38.4MB); trow (12.8MB) aliases bufB. Both are
    // fully consumed by pass2 before concat/spmm write bufA/bufB.
    int2* tmp = (int2*)bufA;
    int* trow = (int*)bufB;

    passA_hist<<<NGROUPS, 256, 0, stream>>>(row, cnt, nnz, nb, epb);
    scan_tiles<<<ntiles2, SCAN_THREADS, 0, stream>>>(cnt, cbase, tile_sums, n2);
    scan_bases<<<1, 64, 0, stream>>>(tile_sums, tile_base, ntiles2);
    add_bases<<<(n2 + 255) / 256, 256, 0, stream>>>(cbase, tile_base, n2, ntiles2);
    passB_scatter<<<NGROUPS, 256, 0, stream>>>(row, col, vals, cbase, tmp, trow, nnz, nb, epb);

    deg_from_bins<<<nb, 256, 0, stream>>>(cbase, trow, deg, n_nodes, nb);
    scan_tiles<<<ntiles1, SCAN_THREADS, 0, stream>>>(deg, offs, tile_sums, n_nodes);
    scan_bases<<<1, 64, 0, stream>>>(tile_sums, tile_base, ntiles1);
    add_bases<<<(n_nodes + 255) / 256, 256, 0, stream>>>(offs, tile_base, n_nodes, ntiles1);
    pass2_place<<<nb, 256, 0, stream>>>(offs, trow, tmp, edat, n_nodes);

    int tot4 = n_nodes * EMBED / 4;
    int nu4 = n_users * EMBED / 4;
    concat_copy<<<2048, 256, 0, stream>>>(user_emb, item_emb, bufA, nu4, tot4);

    int gblocks = (3 * batch * EMBED + 255) / 256;
    int spmm_blocks = (n_nodes + 3) / 4;

    gather_out<<<gblocks, 256, 0, stream>>>(bufA, users, pos, neg, out, batch, n_users, 1);
    spmm<<<spmm_blocks, 256, 0, stream>>>(offs, edat, bufA, bufB, n_nodes);
    gather_out<<<gblocks, 256, 0, stream>>>(bufB, users, pos, neg, out, batch, n_users, 0);
    spmm<<<spmm_blocks, 256, 0, stream>>>(offs, edat, bufB, bufA, n_nodes);
    gather_out<<<gblocks, 256, 0, stream>>>(bufA, users, pos, neg, out, batch, n_users, 0);
    spmm<<<spmm_blocks, 256, 0, stream>>>(offs, edat, bufA, bufB, n_nodes);
    gather_out<<<gblocks, 256, 0, stream>>>(bufB, users, pos, neg, out, batch, n_users, 0);
}